// Round 6
// baseline (544.595 us; speedup 1.0000x reference)
//
#include <hip/hip_runtime.h>
#include <math.h>

typedef __attribute__((ext_vector_type(8))) short short8;
typedef __attribute__((ext_vector_type(4))) float f32x4;
typedef __attribute__((ext_vector_type(2))) unsigned int u32x2;

namespace {
constexpr int Cin = 64, Hin = 256, Win = 256;
constexpr int Cout = 128, Hout = 128, Wout = 128;
constexpr int AF_ENTRIES = 18 * 8 * 64;       // (cb*9+tap)[18] x mchunk[8] x lane[64]
constexpr size_t AF_BYTES = (size_t)AF_ENTRIES * 32;   // {hi short8, lo short8} = 294912 B
constexpr int ROWB = 136;                     // per-iwp column: 64 B hi | 64 B lo | 8 pad
constexpr int IHB  = 129 * ROWB;              // 17544
constexpr int XSB  = 5 * IHB;                 // 87720 B LDS
// fallback direct-conv geometry
constexpr int Bn = 16, CT = 8;
constexpr int NB_FB = (Hout/4) * Bn * (Cout/CT);   // 8192
}

__device__ __forceinline__ void bsplit(float v, unsigned short& h, unsigned short& l) {
    unsigned int uv = __float_as_uint(v);
    h = (unsigned short)(uv >> 16);
    float vh = __uint_as_float((unsigned int)h << 16);
    float r  = v - vh;
    l = (unsigned short)(__float_as_uint(r) >> 16);
}

// ---- pre-kernel: split W into bf16 hi/lo MFMA A-fragments (layout = load order) ----
__global__ __launch_bounds__(256)
void prep_af(const float* __restrict__ w, short8* __restrict__ af) {
    int t = blockIdx.x * 256 + threadIdx.x;
    if (t >= AF_ENTRIES) return;
    int lane = t & 63;
    int mc   = (t >> 6) & 7;     // co chunk (16 co each)
    int tt   = t >> 9;           // cb*9 + tap
    int cb   = tt / 9;
    int tap  = tt % 9;
    int kh = tap / 3, kw = tap % 3;
    int co   = mc * 16 + (lane & 15);
    int cin0 = cb * 32 + (lane >> 4) * 8;
    short8 hi, lo;
#pragma unroll
    for (int i = 0; i < 8; ++i) {
        float v = w[((size_t)(co * Cin + cin0 + i) * 3 + kh) * 3 + kw];
        unsigned short h, l;
        bsplit(v, h, l);
        hi[i] = (short)h; lo[i] = (short)l;
    }
    af[2 * t]     = hi;
    af[2 * t + 1] = lo;
}

// ---- main kernel (implicit GEMM, 3-term bf16 split MFMA) ----
__global__ __launch_bounds__(512, 2)
void conv_mfma(const float* __restrict__ x, const short8* __restrict__ af,
               const float* __restrict__ bias, float* __restrict__ out) {
    __shared__ char xs[XSB] __attribute__((aligned(16)));

    // XCD-bijective swizzle (2048 % 8 == 0, chunk 256)
    int bid = blockIdx.x;
    int swz = (bid & 7) * 256 + (bid >> 3);
    const int owp = swz & 1;          // ow half
    const int ohp = (swz >> 1) & 63;  // oh pair
    const int b   = swz >> 7;         // batch

    const int OW0  = owp * 64;
    const int OH0  = ohp * 2;
    const int iwg0 = 2 * OW0 - 1;     // global iw of iwp==0
    const int ihg0 = 2 * OH0 - 1;     // global ih of ihl==0

    const int t    = threadIdx.x;
    const int lane = t & 63;
    const int wv   = t >> 6;          // wave 0..7
    const int wm   = wv >> 1;         // co group (32 co)
    const int wn   = wv & 1;          // oh_sub
    const int a    = lane & 15;
    const int lq   = lane >> 4;
    const int sq   = t >> 6;          // staging cin-quad (4 cins)

    f32x4 acc[2][4];
#pragma unroll
    for (int mf = 0; mf < 2; ++mf)
#pragma unroll
        for (int nf = 0; nf < 4; ++nf) acc[mf][nf] = (f32x4){0.f, 0.f, 0.f, 0.f};

    short8 pah[2][2], pal[2][2];      // A prefetch double-buffer [buf][mf]
    {   // tt = 0
        int idx = (0 * 8 + wm * 2) * 64 + lane;
        pah[0][0] = af[2 * idx];            pal[0][0] = af[2 * idx + 1];
        pah[0][1] = af[2 * (idx + 64)];     pal[0][1] = af[2 * (idx + 64) + 1];
    }

#pragma unroll
    for (int cb = 0; cb < 2; ++cb) {
        // ---- stage x -> LDS (transposed, bf16 hi/lo, quad-XOR swizzled) ----
        {
            const float* x0 = x + (size_t)(b * Cin + cb * 32 + sq * 4) * (Hin * Win);
#pragma unroll
            for (int ihl = 0; ihl < 5; ++ihl) {
                int ih = ihg0 + ihl;
                bool rv = (ih >= 0);               // ih <= 255 guaranteed
                const float* xrow = x0 + (size_t)(rv ? ih : 0) * Win;
#pragma unroll
                for (int c = 0; c < 3; ++c) {
                    int iwp = lane + 64 * c;
                    if (iwp <= 128) {
                        int iw = iwg0 + iwp;
                        bool ok = rv && (iw >= 0) && (iw <= 255);
                        int iwc = ok ? iw : 0;
                        float v0 = ok ? xrow[iwc]            : 0.f;
                        float v1 = ok ? xrow[iwc + 65536]    : 0.f;
                        float v2 = ok ? xrow[iwc + 2*65536]  : 0.f;
                        float v3 = ok ? xrow[iwc + 3*65536]  : 0.f;
                        unsigned short h0,h1,h2,h3,l0,l1,l2,l3;
                        bsplit(v0,h0,l0); bsplit(v1,h1,l1);
                        bsplit(v2,h2,l2); bsplit(v3,h3,l3);
                        u32x2 hw, lw;
                        hw.x = (unsigned int)h0 | ((unsigned int)h1 << 16);
                        hw.y = (unsigned int)h2 | ((unsigned int)h3 << 16);
                        lw.x = (unsigned int)l0 | ((unsigned int)l1 << 16);
                        lw.y = (unsigned int)l2 | ((unsigned int)l3 << 16);
                        int slot = sq ^ ((iwp >> 1) & 7);
                        int off  = ihl * IHB + iwp * ROWB + slot * 8;
                        *(u32x2*)(xs + off)      = hw;
                        *(u32x2*)(xs + off + 64) = lw;
                    }
                }
            }
        }
        __syncthreads();

        // ---- 9 taps ----
#pragma unroll
        for (int tap = 0; tap < 9; ++tap) {
            const int tt  = cb * 9 + tap;
            const int buf = tt & 1;
            const int kh = tap / 3, kw = tap % 3;

            // prefetch next tap's A fragments (global, crosses barrier legally)
            if (tt + 1 < 18) {
                int idx = ((tt + 1) * 8 + wm * 2) * 64 + lane;
                pah[buf ^ 1][0] = af[2 * idx];            pal[buf ^ 1][0] = af[2 * idx + 1];
                pah[buf ^ 1][1] = af[2 * (idx + 64)];     pal[buf ^ 1][1] = af[2 * (idx + 64) + 1];
            }

            // B fragments from LDS
            short8 bh[4], bl[4];
            const int ihl = 2 * wn + kh;
#pragma unroll
            for (int nf = 0; nf < 4; ++nf) {
                int iwp  = 2 * a + 32 * nf + kw;
                int sm   = (a + 16 * nf + (kw >> 1)) & 7;
                int base = ihl * IHB + iwp * ROWB;
                int s0   = (2 * lq) ^ sm;
                int s1   = s0 ^ 1;
                union { unsigned int u[4]; short8 v; } H, L;
                *(u32x2*)&H.u[0] = *(const u32x2*)(xs + base + s0 * 8);
                *(u32x2*)&H.u[2] = *(const u32x2*)(xs + base + s1 * 8);
                *(u32x2*)&L.u[0] = *(const u32x2*)(xs + base + s0 * 8 + 64);
                *(u32x2*)&L.u[2] = *(const u32x2*)(xs + base + s1 * 8 + 64);
                bh[nf] = H.v; bl[nf] = L.v;
            }

            // 3-term split MFMA; same-acc chains separated for ILP
#pragma unroll
            for (int mf = 0; mf < 2; ++mf)
#pragma unroll
                for (int nf = 0; nf < 4; ++nf)
                    acc[mf][nf] = __builtin_amdgcn_mfma_f32_16x16x32_bf16(pah[buf][mf], bh[nf], acc[mf][nf], 0, 0, 0);
#pragma unroll
            for (int mf = 0; mf < 2; ++mf)
#pragma unroll
                for (int nf = 0; nf < 4; ++nf)
                    acc[mf][nf] = __builtin_amdgcn_mfma_f32_16x16x32_bf16(pah[buf][mf], bl[nf], acc[mf][nf], 0, 0, 0);
#pragma unroll
            for (int mf = 0; mf < 2; ++mf)
#pragma unroll
                for (int nf = 0; nf < 4; ++nf)
                    acc[mf][nf] = __builtin_amdgcn_mfma_f32_16x16x32_bf16(pal[buf][mf], bh[nf], acc[mf][nf], 0, 0, 0);
        }
        __syncthreads();
    }

    // ---- epilogue: bias - 0.5, hardswish, mish ----
    const int oh = OH0 + wn;
#pragma unroll
    for (int mf = 0; mf < 2; ++mf) {
#pragma unroll
        for (int r = 0; r < 4; ++r) {
            int co = wm * 32 + mf * 16 + lq * 4 + r;
            float bs = bias[co] - 0.5f;
#pragma unroll
            for (int nf = 0; nf < 4; ++nf) {
                int ow = OW0 + nf * 16 + a;
                float z  = acc[mf][nf][r] + bs;
                float cc = fminf(fmaxf(z + 3.0f, 0.0f), 6.0f);
                float hs = z * cc * (1.0f / 6.0f);
                float u  = __expf(hs);
                float w2 = u * (u + 2.0f);
                float res = (hs > 15.0f) ? hs : hs * w2 / (w2 + 2.0f);
                out[(((size_t)b * Cout + co) * Hout + oh) * Wout + ow] = res;
            }
        }
    }
}

// ---- fallback: fp32 direct conv (no workspace needed) ----
__global__ __launch_bounds__(256)
void conv3x3s2_fused(const float* __restrict__ x,
                     const float* __restrict__ w,
                     const float* __restrict__ bias,
                     float* __restrict__ out) {
    const int orig = blockIdx.x;
    const int swz  = (orig & 7) * (NB_FB / 8) + (orig >> 3);
    const int cg   = swz & 15;
    const int rest = swz >> 4;
    const int ohp4 = rest & 31;
    const int b    = rest >> 5;

    const int ow  = threadIdx.x;
    const int oh0 = ohp4 * 4 + threadIdx.y * 2;
    const int c0  = cg * CT;

    const int iw0 = 2 * ow - 1;
    const int ih0 = 2 * oh0 - 1;
    const bool left = (iw0 < 0);
    const bool top  = (ih0 < 0);
    const int iwA  = left ? 0 : iw0;

    float acc[2][CT];
#pragma unroll
    for (int r = 0; r < 2; ++r)
#pragma unroll
        for (int c = 0; c < CT; ++c) acc[r][c] = 0.0f;

    const float* xb = x + (size_t)b * Cin * Hin * Win;

    for (int cin = 0; cin < Cin; ++cin) {
        const float* xc = xb + (size_t)cin * Hin * Win;
        float in[5][3];
#pragma unroll
        for (int r = 0; r < 5; ++r) {
            const int ih  = ih0 + r;
            const int ihc = (top && r == 0) ? 0 : ih;
            const float* row = xc + (size_t)ihc * Win;
            float  v0  = row[iwA];
            float2 v12 = *reinterpret_cast<const float2*>(row + (iw0 + 1));
            if (left) v0 = 0.0f;
            if (top && r == 0) { v0 = 0.0f; v12.x = 0.0f; v12.y = 0.0f; }
            in[r][0] = v0; in[r][1] = v12.x; in[r][2] = v12.y;
        }
#pragma unroll
        for (int c = 0; c < CT; ++c) {
            const float* wc = w + ((size_t)(c0 + c) * Cin + cin) * 9;
#pragma unroll
            for (int kh = 0; kh < 3; ++kh)
#pragma unroll
                for (int kw = 0; kw < 3; ++kw) {
                    const float wv = wc[kh * 3 + kw];
                    acc[0][c] = fmaf(in[kh][kw],     wv, acc[0][c]);
                    acc[1][c] = fmaf(in[kh + 2][kw], wv, acc[1][c]);
                }
        }
    }

#pragma unroll
    for (int c = 0; c < CT; ++c) {
        const float bs = bias[c0 + c] - 0.5f;
#pragma unroll
        for (int r = 0; r < 2; ++r) {
            float z  = acc[r][c] + bs;
            float cc = fminf(fmaxf(z + 3.0f, 0.0f), 6.0f);
            float hs = z * cc * (1.0f / 6.0f);
            float u  = __expf(hs);
            float w2 = u * (u + 2.0f);
            float res = (hs > 15.0f) ? hs : hs * w2 / (w2 + 2.0f);
            out[(((size_t)b * Cout + (c0 + c)) * Hout + (oh0 + r)) * Wout + ow] = res;
        }
    }
}

extern "C" void kernel_launch(void* const* d_in, const int* in_sizes, int n_in,
                              void* d_out, int out_size, void* d_ws, size_t ws_size,
                              hipStream_t stream) {
    (void)in_sizes; (void)n_in; (void)out_size;
    const float* x    = (const float*)d_in[0];
    const float* w    = (const float*)d_in[1];
    const float* bias = (const float*)d_in[2];
    float* out        = (float*)d_out;

    if (ws_size >= AF_BYTES && d_ws != nullptr) {
        short8* af = (short8*)d_ws;
        prep_af<<<AF_ENTRIES / 256, 256, 0, stream>>>(w, af);
        conv_mfma<<<2048, 512, 0, stream>>>(x, af, bias, out);
    } else {
        // workspace too small for weight fragments: fp32 direct conv fallback
        dim3 block(128, 2);
        conv3x3s2_fused<<<NB_FB, block, 0, stream>>>(x, w, bias, out);
    }
}